// Round 17
// baseline (204.801 us; speedup 1.0000x reference)
//
#include <hip/hip_runtime.h>

#define CDIM 128
#define NC   8388608

typedef __attribute__((ext_vector_type(8)))  short bf8v;   // 8 bf16 (4 VGPRs)
typedef __attribute__((ext_vector_type(16))) float f32x16; // MFMA 32x32 acc

// ws layout (float offsets):
//   nrm  @0       (1024)
//   DT   @1024    (122880)
//   Bph  @123904  (61440)
//   Bpl  @185344  (61440)
//   keys @246784  (262144 ints)
//   partials @508928 (1024)

__device__ __forceinline__ void bsplit(float v, short& h, short& lo) {
  unsigned u = __float_as_uint(v);
  unsigned hb = (u + 0x7fffu + ((u >> 16) & 1u)) >> 16;   // RNE to bf16
  float hf = __uint_as_float(hb << 16);
  float lf = v - hf;
  unsigned u2 = __float_as_uint(lf);
  unsigned lb = (u2 + 0x7fffu + ((u2 >> 16) & 1u)) >> 16;
  h = (short)hb; lo = (short)lb;
}

// ---- kernel 0 (fused): blocks 0..59 pack dicts; blocks 60..63 norms + DT ----
__global__ void vq_prep(const float* __restrict__ D0, const float* __restrict__ D1,
                        const float* __restrict__ D2, const float* __restrict__ D3,
                        float* __restrict__ nrm, float* __restrict__ DT,
                        bf8v* __restrict__ Bph, bf8v* __restrict__ Bpl) {
  const int b = blockIdx.x;
  if (b < 60) {
    int g = b * 256 + threadIdx.x;                  // 15360 exact
    int T = g >> 9, c = (g >> 6) & 7, l = g & 63;
    int col = T * 32 + (l & 31);
    int k0 = c * 16 + (l >> 5) * 8;
    const float* D; int K, cb;
    if (col < 64)       { D = D0; K = 64;  cb = col; }
    else if (col < 192) { D = D1; K = 128; cb = col - 64; }
    else if (col < 448) { D = D2; K = 256; cb = col - 192; }
    else                { D = D3; K = 512; cb = col - 448; }
    short h0,h1,h2,h3,h4,h5,h6,h7, q0,q1,q2,q3,q4,q5,q6,q7;
    bsplit(D[(k0+0)*K + cb], h0, q0);
    bsplit(D[(k0+1)*K + cb], h1, q1);
    bsplit(D[(k0+2)*K + cb], h2, q2);
    bsplit(D[(k0+3)*K + cb], h3, q3);
    bsplit(D[(k0+4)*K + cb], h4, q4);
    bsplit(D[(k0+5)*K + cb], h5, q5);
    bsplit(D[(k0+6)*K + cb], h6, q6);
    bsplit(D[(k0+7)*K + cb], h7, q7);
    Bph[g] = (bf8v){h0,h1,h2,h3,h4,h5,h6,h7};
    Bpl[g] = (bf8v){q0,q1,q2,q3,q4,q5,q6,q7};
  } else {
    int g = (b - 60) * 256 + threadIdx.x;
    if (g >= 960) return;
    const float* D; int K, k; float* T;
    if (g < 64)       { D = D0; K = 64;  k = g;       T = DT; }
    else if (g < 192) { D = D1; K = 128; k = g - 64;  T = DT + 8192; }
    else if (g < 448) { D = D2; K = 256; k = g - 192; T = DT + 24576; }
    else              { D = D3; K = 512; k = g - 448; T = DT + 57344; }
    float s = 0.f;
    for (int c = 0; c < 128; ++c) { float v = D[c*K+k]; s = fmaf(v,v,s); T[k*128+c] = v; }
    nrm[g] = s;
  }
}

#define MK8(U0, U1, HD, LD) { \
  short h0,h1,h2,h3,h4,h5,h6,h7, q0,q1,q2,q3,q4,q5,q6,q7; \
  bsplit(U0.x,h0,q0); bsplit(U0.y,h1,q1); bsplit(U0.z,h2,q2); bsplit(U0.w,h3,q3); \
  bsplit(U1.x,h4,q4); bsplit(U1.y,h5,q5); bsplit(U1.z,h6,q6); bsplit(U1.w,h7,q7); \
  HD = (bf8v){h0,h1,h2,h3,h4,h5,h6,h7}; \
  LD = (bf8v){q0,q1,q2,q3,q4,q5,q6,q7}; }

#define MFMA32(AC, AF, BF) AC = __builtin_amdgcn_mfma_f32_32x32x16_bf16((AF), (BF), (AC), 0, 0, 0)

// stage tiles for the next round into per-part buffers (all 256 threads help)
#define STAGE17(TP0, TP1, DO0) { \
  if (DO0) { \
    BL[0][t]       = Bph[(TP0) * 512 + t]; \
    BL[0][256 + t] = Bph[(TP0) * 512 + 256 + t]; \
    BL[0][512 + t] = Bpl[(TP0) * 512 + t]; \
    BL[0][768 + t] = Bpl[(TP0) * 512 + 256 + t]; \
  } \
  BL[1][t]       = Bph[(TP1) * 512 + t]; \
  BL[1][256 + t] = Bph[(TP1) * 512 + 256 + t]; \
  BL[1][512 + t] = Bpl[(TP1) * 512 + t]; \
  BL[1][768 + t] = Bpl[(TP1) * 512 + 256 + t]; }

// one 32-col tile from this wave's part buffer (runtime tile index TT for nrm/col)
#define COMPUTE17(TT) { \
  f32x16 ae = zero16, ao = zero16; \
  _Pragma("unroll") \
  for (int cp = 0; cp < 4; ++cp) { \
    const int ce = 2*cp, co = 2*cp+1; \
    bf8v bhe = BL[part][ce*64 + l]; bf8v bho = BL[part][co*64 + l]; \
    bf8v ble = BL[part][512 + ce*64 + l]; bf8v blo = BL[part][512 + co*64 + l]; \
    MFMA32(ae, Ah[ce], bhe); MFMA32(ao, Ah[co], bho); \
    MFMA32(ae, Al[ce], bhe); MFMA32(ao, Al[co], bho); \
    MFMA32(ae, Ah[ce], ble); MFMA32(ao, Ah[co], blo); \
  } \
  f32x16 sv = ae + ao; \
  const float nv = nrm_g[(TT)*32 + (l & 31)]; \
  const int colT = (TT)*32 + (l & 31); \
  _Pragma("unroll") \
  for (int r = 0; r < 16; ++r) { \
    float c0 = fmaf(-2.f, sv[r], nv); \
    if (c0 < bc[r]) { bc[r] = c0; bk[r] = colT; } } }

// lex-min argmin flush (runtime dict/base/gamma); closed-form loss; reset
#define FLUSH17(DICTID, BASE, GAM) { \
  _Pragma("unroll") \
  for (int r = 0; r < 16; ++r) { \
    float b0 = bc[r]; int K0 = bk[r]; \
    _Pragma("unroll") \
    for (int m = 1; m <= 16; m <<= 1) { \
      float pb = __shfl_xor(b0, m); int pk = __shfl_xor(K0, m); \
      if (pb < b0 || (pb == b0 && pk < K0)) { b0 = pb; K0 = pk; } } \
    if ((l & 31) == 0) { \
      const int ro = (r & 3) + 8 * (r >> 2) + 4 * hl; \
      keys[((rowbase + ro) << 2) | (DICTID)] = K0 - (BASE); \
      const float nst = nrm_g[K0]; \
      lossacc = fmaf((GAM) * a, fmaf(am1, nst, b0), lossacc); } \
    bc[r] = 1e30f; bk[r] = 0; } }

// ---- kernel 1: MFMA scoring + argmin + loss. 1024 blocks x 256 thr.
// 4 waves = {2 row-tiles} x {2 dict-parts}; part 0: tiles 0..13 (dicts 0-2),
// part 1: tiles 14..29 (dict 3). 32 KB LDS -> 4 blocks/CU -> 16 waves/CU.
__global__ __launch_bounds__(256, 4) void vq_mfma(
    const float* __restrict__ x,
    const bf8v* __restrict__ Bph, const bf8v* __restrict__ Bpl,
    const float* __restrict__ nrm_g,
    const float* __restrict__ alpha_p, const float* __restrict__ gamma_p,
    int* __restrict__ keys, float* __restrict__ partials)
{
  __shared__ bf8v  BL[2][1024];   // [part][tile data] 32 KB
  __shared__ float lossW[4];

  const int t = threadIdx.x;
  const int w = t >> 6, l = t & 63;
  const int hl = l >> 5;
  const int rowt = w & 1;
  const int part = w >> 1;
  const int rowbase = blockIdx.x * 64 + rowt * 32;

  const float a   = alpha_p[0];
  const float am1 = a - 1.f;
  const float g0 = gamma_p[0], g1 = gamma_p[1], g2 = gamma_p[2], g3 = gamma_p[3];
  const float gsum = g0 + g1 + g2 + g3;

  // A fragments straight from global; exact xsq accumulated pre-split
  bf8v Ah[8], Al[8];
  float xsqh = 0.f;
  {
    const float* __restrict__ xr = x + (size_t)(rowbase + (l & 31)) * CDIM + hl * 8;
    #pragma unroll
    for (int c = 0; c < 8; ++c) {
      float4 u0 = *(const float4*)(xr + c * 16);
      float4 u1 = *(const float4*)(xr + c * 16 + 4);
      xsqh = fmaf(u0.x,u0.x, xsqh); xsqh = fmaf(u0.y,u0.y, xsqh);
      xsqh = fmaf(u0.z,u0.z, xsqh); xsqh = fmaf(u0.w,u0.w, xsqh);
      xsqh = fmaf(u1.x,u1.x, xsqh); xsqh = fmaf(u1.y,u1.y, xsqh);
      xsqh = fmaf(u1.z,u1.z, xsqh); xsqh = fmaf(u1.w,u1.w, xsqh);
      MK8(u0, u1, Ah[c], Al[c])
    }
  }
  float xs_ = xsqh;
  #pragma unroll
  for (int m = 1; m <= 32; m <<= 1) xs_ += __shfl_xor(xs_, m);

  f32x16 zero16;
  #pragma unroll
  for (int i = 0; i < 16; ++i) zero16[i] = 0.f;

  float bc[16]; int bk[16];
  #pragma unroll
  for (int r = 0; r < 16; ++r) { bc[r] = 1e30f; bk[r] = 0; }
  float lossacc = 0.f;

  STAGE17(0, 14, true)
  __syncthreads();

  #pragma unroll 1
  for (int r16i = 0; r16i < 16; ++r16i) {
    if (part == 1) { COMPUTE17(14 + r16i) }
    else if (r16i < 14) { COMPUTE17(r16i) }
    if (part == 0) {
      if (r16i == 1)       FLUSH17(0,   0, g0)
      else if (r16i == 5)  FLUSH17(1,  64, g1)
      else if (r16i == 13) FLUSH17(2, 192, g2)
    } else if (r16i == 15) FLUSH17(3, 448, g3)
    __syncthreads();
    if (r16i < 15) {
      const int n0 = (r16i + 1 < 14) ? r16i + 1 : 13;
      STAGE17(n0, 15 + r16i, (r16i + 1 < 14))
      __syncthreads();
    }
  }

  // loss: flush terms live in lanes 0 and 32; part-0 waves add gsum*xsq once
  {
    float wl = lossacc + __shfl_xor(lossacc, 32);
    if (l == 0) lossW[w] = (part == 0) ? fmaf(gsum, xs_, wl) : wl;
  }
  __syncthreads();
  if (t == 0) partials[blockIdx.x] = lossW[0] + lossW[1] + lossW[2] + lossW[3];
}

// ---- kernel 2: out-only gather (no x read, no loss). 2048 blocks x 256 thr ----
__global__ __launch_bounds__(256, 8) void vq_merge(
    const float* __restrict__ DT, const int* __restrict__ keys,
    const float* __restrict__ alpha_p, const float* __restrict__ gamma_p,
    float* __restrict__ out)
{
  __shared__ int kk[32][4];
  const int t = threadIdx.x;
  const int row0 = blockIdx.x * 32;
  if (t < 128) kk[t >> 2][t & 3] = keys[((row0 + (t >> 2)) << 2) | (t & 3)];
  __syncthreads();
  const float a = alpha_p[0];
  const float g0 = gamma_p[0], g1 = gamma_p[1], g2 = gamma_p[2], g3 = gamma_p[3];
  #pragma unroll
  for (int j = 0; j < 4; ++j) {
    const int f = j * 256 + t;
    const int r = f >> 5, c4 = (f & 31) * 4;
    const size_t off = (size_t)(row0 + r) * CDIM + c4;
    const float4 d0 = *(const float4*)(DT +         kk[r][0] * 128 + c4);
    const float4 d1 = *(const float4*)(DT +  8192 + kk[r][1] * 128 + c4);
    const float4 d2 = *(const float4*)(DT + 24576 + kk[r][2] * 128 + c4);
    const float4 d3 = *(const float4*)(DT + 57344 + kk[r][3] * 128 + c4);
    float4 o;
    o.x = a * (g0*d0.x + g1*d1.x + g2*d2.x + g3*d3.x);
    o.y = a * (g0*d0.y + g1*d1.y + g2*d2.y + g3*d3.y);
    o.z = a * (g0*d0.z + g1*d1.z + g2*d2.z + g3*d3.z);
    o.w = a * (g0*d0.w + g1*d1.w + g2*d2.w + g3*d3.w);
    *(float4*)(out + off) = o;
  }
}

// ---- kernel 3: final deterministic loss reduction (1024 partials) ----
__global__ void vq_loss(const float* __restrict__ partials, float* __restrict__ lossp) {
  __shared__ float wr[4];
  const int t = threadIdx.x;
  float v = partials[t] + partials[t + 256] + partials[t + 512] + partials[t + 768];
  #pragma unroll
  for (int off = 32; off > 0; off >>= 1) v += __shfl_down(v, off);
  if ((t & 63) == 0) wr[t >> 6] = v;
  __syncthreads();
  if (t == 0) lossp[0] = (wr[0] + wr[1] + wr[2] + wr[3]) * (1.25f / 8388608.f);
}

extern "C" void kernel_launch(void* const* d_in, const int* in_sizes, int n_in,
                              void* d_out, int out_size, void* d_ws, size_t ws_size,
                              hipStream_t stream) {
  const float* x  = (const float*)d_in[0];
  const float* D0 = (const float*)d_in[1];
  const float* D1 = (const float*)d_in[2];
  const float* D2 = (const float*)d_in[3];
  const float* D3 = (const float*)d_in[4];
  const float* alpha = (const float*)d_in[5];
  const float* gamma = (const float*)d_in[6];
  float* out = (float*)d_out;

  float* ws  = (float*)d_ws;
  float* nrm = ws;                         // 1024
  float* DT  = ws + 1024;                  // 122880
  bf8v*  Bph = (bf8v*)(ws + 123904);       // 61440 floats
  bf8v*  Bpl = (bf8v*)(ws + 185344);       // 61440 floats
  int*  keys = (int*)(ws + 246784);        // 262144 ints
  float* partials = ws + 508928;           // 1024

  vq_prep<<<64, 256, 0, stream>>>(D0, D1, D2, D3, nrm, DT, Bph, Bpl);
  vq_mfma<<<1024, 256, 0, stream>>>(x, Bph, Bpl, nrm, alpha, gamma, keys, partials);
  vq_merge<<<2048, 256, 0, stream>>>(DT, keys, alpha, gamma, out);
  vq_loss<<<1, 256, 0, stream>>>(partials, out + NC);
}

// Round 18
// 176.878 us; speedup vs baseline: 1.1579x; 1.1579x over previous
//
#include <hip/hip_runtime.h>
#include <stdint.h>

#define CDIM 128
#define NC   8388608

typedef __attribute__((ext_vector_type(8)))  short bf8v;   // 8 bf16 (4 VGPRs)
typedef __attribute__((ext_vector_type(16))) float f32x16; // MFMA 32x32 acc

// ws layout (float offsets):
//   nrm  @0       (1024)
//   DT   @1024    (122880)
//   Bph  @123904  (61440)
//   Bpl  @185344  (61440)
//   keys @246784  (262144 ints)
//   partials @508928 (512)

__device__ __forceinline__ void bsplit(float v, short& h, short& lo) {
  unsigned u = __float_as_uint(v);
  unsigned hb = (u + 0x7fffu + ((u >> 16) & 1u)) >> 16;   // RNE to bf16
  float hf = __uint_as_float(hb << 16);
  float lf = v - hf;
  unsigned u2 = __float_as_uint(lf);
  unsigned lb = (u2 + 0x7fffu + ((u2 >> 16) & 1u)) >> 16;
  h = (short)hb; lo = (short)lb;
}

// ---- kernel 0 (fused): blocks 0..59 pack dicts; blocks 60..63 norms + DT ----
__global__ void vq_prep(const float* __restrict__ D0, const float* __restrict__ D1,
                        const float* __restrict__ D2, const float* __restrict__ D3,
                        float* __restrict__ nrm, float* __restrict__ DT,
                        bf8v* __restrict__ Bph, bf8v* __restrict__ Bpl) {
  const int b = blockIdx.x;
  if (b < 60) {
    int g = b * 256 + threadIdx.x;                  // 15360 exact
    int T = g >> 9, c = (g >> 6) & 7, l = g & 63;
    int col = T * 32 + (l & 31);
    int k0 = c * 16 + (l >> 5) * 8;
    const float* D; int K, cb;
    if (col < 64)       { D = D0; K = 64;  cb = col; }
    else if (col < 192) { D = D1; K = 128; cb = col - 64; }
    else if (col < 448) { D = D2; K = 256; cb = col - 192; }
    else                { D = D3; K = 512; cb = col - 448; }
    short h0,h1,h2,h3,h4,h5,h6,h7, q0,q1,q2,q3,q4,q5,q6,q7;
    bsplit(D[(k0+0)*K + cb], h0, q0);
    bsplit(D[(k0+1)*K + cb], h1, q1);
    bsplit(D[(k0+2)*K + cb], h2, q2);
    bsplit(D[(k0+3)*K + cb], h3, q3);
    bsplit(D[(k0+4)*K + cb], h4, q4);
    bsplit(D[(k0+5)*K + cb], h5, q5);
    bsplit(D[(k0+6)*K + cb], h6, q6);
    bsplit(D[(k0+7)*K + cb], h7, q7);
    Bph[g] = (bf8v){h0,h1,h2,h3,h4,h5,h6,h7};
    Bpl[g] = (bf8v){q0,q1,q2,q3,q4,q5,q6,q7};
  } else {
    int g = (b - 60) * 256 + threadIdx.x;
    if (g >= 960) return;
    const float* D; int K, k; float* T;
    if (g < 64)       { D = D0; K = 64;  k = g;       T = DT; }
    else if (g < 192) { D = D1; K = 128; k = g - 64;  T = DT + 8192; }
    else if (g < 448) { D = D2; K = 256; k = g - 192; T = DT + 24576; }
    else              { D = D3; K = 512; k = g - 448; T = DT + 57344; }
    float s = 0.f;
    for (int c = 0; c < 128; ++c) { float v = D[c*K+k]; s = fmaf(v,v,s); T[k*128+c] = v; }
    nrm[g] = s;
  }
}

#define MK8(U0, U1, HD, LD) { \
  short h0,h1,h2,h3,h4,h5,h6,h7, q0,q1,q2,q3,q4,q5,q6,q7; \
  bsplit(U0.x,h0,q0); bsplit(U0.y,h1,q1); bsplit(U0.z,h2,q2); bsplit(U0.w,h3,q3); \
  bsplit(U1.x,h4,q4); bsplit(U1.y,h5,q5); bsplit(U1.z,h6,q6); bsplit(U1.w,h7,q7); \
  HD = (bf8v){h0,h1,h2,h3,h4,h5,h6,h7}; \
  LD = (bf8v){q0,q1,q2,q3,q4,q5,q6,q7}; }

#define MFMA32(AC, AF, BF) AC = __builtin_amdgcn_mfma_f32_32x32x16_bf16((AF), (BF), (AC), 0, 0, 0)

// direct global->LDS (CK-style casts); size literal 16
#define GLDS(SRC, DST) \
  __builtin_amdgcn_global_load_lds( \
      (const __attribute__((address_space(1))) unsigned int*)(uintptr_t)(SRC), \
      (__attribute__((address_space(3))) unsigned int*)(uintptr_t)(DST), 16, 0, 0)

// stage one 64-col round (2 sub-tiles, hi+lo = 32 KB) into BL[BUF] via global_load_lds.
// entry f = j*256 + t; sub-tile s=f>>10, half h=(f>>9)&1, idx=f&511.
// LDS dest base is wave-uniform (j*256 + t&192); HW adds lane*16.
#define STAGE64(TP, BUF) { \
  _Pragma("unroll") \
  for (int j = 0; j < 8; ++j) { \
    const int s_ = j >> 2, h_ = (j >> 1) & 1; \
    const bf8v* src_ = (h_ ? Bpl : Bph) + ((TP) + s_) * 512 + (j & 1) * 256 + t; \
    GLDS(src_, &BL[BUF][j * 256 + wbase]); \
  } }

// one 64-col round from BL[BUF]: 32 ds_read_b128 + 48 MFMAs (4 indep chains) + criterion.
// Per-acc chain order identical to r15/r16 (bit-identical accumulation).
#define COMPUTE64(R, BUF) { \
  f32x16 ae0 = zero16, ao0 = zero16, ae1 = zero16, ao1 = zero16; \
  _Pragma("unroll") \
  for (int cp = 0; cp < 4; ++cp) { \
    const int ce = 2*cp, co = 2*cp+1; \
    bf8v b0he = BL[BUF][ce*64 + l];        bf8v b0ho = BL[BUF][co*64 + l]; \
    bf8v b0le = BL[BUF][512 + ce*64 + l];  bf8v b0lo = BL[BUF][512 + co*64 + l]; \
    bf8v b1he = BL[BUF][1024 + ce*64 + l]; bf8v b1ho = BL[BUF][1024 + co*64 + l]; \
    bf8v b1le = BL[BUF][1536 + ce*64 + l]; bf8v b1lo = BL[BUF][1536 + co*64 + l]; \
    MFMA32(ae0, Ah[ce], b0he); MFMA32(ao0, Ah[co], b0ho); \
    MFMA32(ae1, Ah[ce], b1he); MFMA32(ao1, Ah[co], b1ho); \
    MFMA32(ae0, Al[ce], b0he); MFMA32(ao0, Al[co], b0ho); \
    MFMA32(ae1, Al[ce], b1he); MFMA32(ao1, Al[co], b1ho); \
    MFMA32(ae0, Ah[ce], b0le); MFMA32(ao0, Ah[co], b0lo); \
    MFMA32(ae1, Ah[ce], b1le); MFMA32(ao1, Ah[co], b1lo); \
  } \
  { f32x16 sv = ae0 + ao0; \
    const float nv = nrm_g[(2*(R))*32 + (l & 31)]; \
    const int colT = (2*(R))*32 + (l & 31); \
    _Pragma("unroll") \
    for (int r = 0; r < 16; ++r) { \
      float c0 = fmaf(-2.f, sv[r], nv); \
      if (c0 < bc[r]) { bc[r] = c0; bk[r] = colT; } } } \
  { f32x16 sv = ae1 + ao1; \
    const float nv = nrm_g[(2*(R)+1)*32 + (l & 31)]; \
    const int colT = (2*(R)+1)*32 + (l & 31); \
    _Pragma("unroll") \
    for (int r = 0; r < 16; ++r) { \
      float c0 = fmaf(-2.f, sv[r], nv); \
      if (c0 < bc[r]) { bc[r] = c0; bk[r] = colT; } } } }

// lex-min argmin flush; keys -> global; closed-form loss; reset
#define FLUSHG(DICTID, BASE, GAM) { \
  _Pragma("unroll") \
  for (int r = 0; r < 16; ++r) { \
    float b0 = bc[r]; int K0 = bk[r]; \
    _Pragma("unroll") \
    for (int m = 1; m <= 16; m <<= 1) { \
      float pb = __shfl_xor(b0, m); int pk = __shfl_xor(K0, m); \
      if (pb < b0 || (pb == b0 && pk < K0)) { b0 = pb; K0 = pk; } } \
    if ((l & 31) == 0) { \
      const int ro = (r & 3) + 8 * (r >> 2) + 4 * hl; \
      keys[((rowbase + ro) << 2) | (DICTID)] = K0 - (BASE); \
      const float nst = nrm_g[K0]; \
      lossacc = fmaf((GAM) * a, fmaf(am1, nst, b0), lossacc); } \
    bc[r] = 1e30f; bk[r] = 0; } }

#define RND(R) { \
  if ((R) < 14) STAGE64(2*((R)+1), ((R)+1) & 1) \
  COMPUTE64(R, (R) & 1) }

// ---- kernel 1: MFMA scoring + argmin + loss. 512 blocks x 256 thr, 128 rows/block.
// 15 x 64-col rounds, dbuf LDS via global_load_lds, one barrier per round.
__global__ __launch_bounds__(256, 2) void vq_mfma(
    const float* __restrict__ x,
    const bf8v* __restrict__ Bph, const bf8v* __restrict__ Bpl,
    const float* __restrict__ nrm_g,
    const float* __restrict__ alpha_p, const float* __restrict__ gamma_p,
    int* __restrict__ keys, float* __restrict__ partials)
{
  __shared__ bf8v  BL[2][2048];   // 64 KB: two 64-col round buffers
  __shared__ float lossW[4];

  const int t = threadIdx.x;
  const int w = t >> 6, l = t & 63;
  const int hl = l >> 5;
  const int wbase = t & 192;      // wave-uniform lane-group base for global_load_lds
  const int rowbase = blockIdx.x * 128 + w * 32;

  const float a   = alpha_p[0];
  const float am1 = a - 1.f;
  const float g0 = gamma_p[0], g1 = gamma_p[1], g2 = gamma_p[2], g3 = gamma_p[3];
  const float gsum = g0 + g1 + g2 + g3;

  // A fragments straight from global; exact xsq accumulated pre-split
  bf8v Ah[8], Al[8];
  float xsqh = 0.f;
  {
    const float* __restrict__ xr = x + (size_t)(rowbase + (l & 31)) * CDIM + hl * 8;
    #pragma unroll
    for (int c = 0; c < 8; ++c) {
      float4 u0 = *(const float4*)(xr + c * 16);
      float4 u1 = *(const float4*)(xr + c * 16 + 4);
      xsqh = fmaf(u0.x,u0.x, xsqh); xsqh = fmaf(u0.y,u0.y, xsqh);
      xsqh = fmaf(u0.z,u0.z, xsqh); xsqh = fmaf(u0.w,u0.w, xsqh);
      xsqh = fmaf(u1.x,u1.x, xsqh); xsqh = fmaf(u1.y,u1.y, xsqh);
      xsqh = fmaf(u1.z,u1.z, xsqh); xsqh = fmaf(u1.w,u1.w, xsqh);
      MK8(u0, u1, Ah[c], Al[c])
    }
  }
  float xs_ = xsqh;
  #pragma unroll
  for (int m = 1; m <= 32; m <<= 1) xs_ += __shfl_xor(xs_, m);

  f32x16 zero16;
  #pragma unroll
  for (int i = 0; i < 16; ++i) zero16[i] = 0.f;

  float bc[16]; int bk[16];
  #pragma unroll
  for (int r = 0; r < 16; ++r) { bc[r] = 1e30f; bk[r] = 0; }
  float lossacc = 0.f;

  STAGE64(0, 0)
  __syncthreads();                       // vmcnt drained: round-0 tiles resident

  RND(0)  FLUSHG(0,   0, g0)  __syncthreads();
  RND(1)  __syncthreads();
  RND(2)  FLUSHG(1,  64, g1)  __syncthreads();
  RND(3)  __syncthreads();
  RND(4)  __syncthreads();
  RND(5)  __syncthreads();
  RND(6)  FLUSHG(2, 192, g2)  __syncthreads();
  RND(7)  __syncthreads();
  RND(8)  __syncthreads();
  RND(9)  __syncthreads();
  RND(10) __syncthreads();
  RND(11) __syncthreads();
  RND(12) __syncthreads();
  RND(13) __syncthreads();
  RND(14) FLUSHG(3, 448, g3)

  // loss: flush terms live in lanes 0 and 32; add gsum * wave xsq once
  {
    float wl = lossacc + __shfl_xor(lossacc, 32);
    if (l == 0) lossW[w] = fmaf(gsum, xs_, wl);
  }
  __syncthreads();
  if (t == 0) partials[blockIdx.x] = lossW[0] + lossW[1] + lossW[2] + lossW[3];
}

// ---- kernel 2: out-only gather (no x read, no loss). 2048 blocks x 256 thr ----
__global__ __launch_bounds__(256, 8) void vq_merge(
    const float* __restrict__ DT, const int* __restrict__ keys,
    const float* __restrict__ alpha_p, const float* __restrict__ gamma_p,
    float* __restrict__ out)
{
  __shared__ int kk[32][4];
  const int t = threadIdx.x;
  const int row0 = blockIdx.x * 32;
  if (t < 128) kk[t >> 2][t & 3] = keys[((row0 + (t >> 2)) << 2) | (t & 3)];
  __syncthreads();
  const float a = alpha_p[0];
  const float g0 = gamma_p[0], g1 = gamma_p[1], g2 = gamma_p[2], g3 = gamma_p[3];
  #pragma unroll
  for (int j = 0; j < 4; ++j) {
    const int f = j * 256 + t;
    const int r = f >> 5, c4 = (f & 31) * 4;
    const size_t off = (size_t)(row0 + r) * CDIM + c4;
    const float4 d0 = *(const float4*)(DT +         kk[r][0] * 128 + c4);
    const float4 d1 = *(const float4*)(DT +  8192 + kk[r][1] * 128 + c4);
    const float4 d2 = *(const float4*)(DT + 24576 + kk[r][2] * 128 + c4);
    const float4 d3 = *(const float4*)(DT + 57344 + kk[r][3] * 128 + c4);
    float4 o;
    o.x = a * (g0*d0.x + g1*d1.x + g2*d2.x + g3*d3.x);
    o.y = a * (g0*d0.y + g1*d1.y + g2*d2.y + g3*d3.y);
    o.z = a * (g0*d0.z + g1*d1.z + g2*d2.z + g3*d3.z);
    o.w = a * (g0*d0.w + g1*d1.w + g2*d2.w + g3*d3.w);
    *(float4*)(out + off) = o;
  }
}

// ---- kernel 3: final deterministic loss reduction (512 partials) ----
__global__ void vq_loss(const float* __restrict__ partials, float* __restrict__ lossp) {
  __shared__ float wr[4];
  const int t = threadIdx.x;
  float v = partials[t] + partials[t + 256];
  #pragma unroll
  for (int off = 32; off > 0; off >>= 1) v += __shfl_down(v, off);
  if ((t & 63) == 0) wr[t >> 6] = v;
  __syncthreads();
  if (t == 0) lossp[0] = (wr[0] + wr[1] + wr[2] + wr[3]) * (1.25f / 8388608.f);
}

extern "C" void kernel_launch(void* const* d_in, const int* in_sizes, int n_in,
                              void* d_out, int out_size, void* d_ws, size_t ws_size,
                              hipStream_t stream) {
  const float* x  = (const float*)d_in[0];
  const float* D0 = (const float*)d_in[1];
  const float* D1 = (const float*)d_in[2];
  const float* D2 = (const float*)d_in[3];
  const float* D3 = (const float*)d_in[4];
  const float* alpha = (const float*)d_in[5];
  const float* gamma = (const float*)d_in[6];
  float* out = (float*)d_out;

  float* ws  = (float*)d_ws;
  float* nrm = ws;                         // 1024
  float* DT  = ws + 1024;                  // 122880
  bf8v*  Bph = (bf8v*)(ws + 123904);       // 61440 floats
  bf8v*  Bpl = (bf8v*)(ws + 185344);       // 61440 floats
  int*  keys = (int*)(ws + 246784);        // 262144 ints
  float* partials = ws + 508928;           // 512

  vq_prep<<<64, 256, 0, stream>>>(D0, D1, D2, D3, nrm, DT, Bph, Bpl);
  vq_mfma<<<512, 256, 0, stream>>>(x, Bph, Bpl, nrm, alpha, gamma, keys, partials);
  vq_merge<<<2048, 256, 0, stream>>>(DT, keys, alpha, gamma, out);
  vq_loss<<<1, 256, 0, stream>>>(partials, out + NC);
}

// Round 19
// 99.220 us; speedup vs baseline: 2.0641x; 1.7827x over previous
//
#include <hip/hip_runtime.h>

#define CDIM 128
#define NC   8388608

typedef __attribute__((ext_vector_type(8)))  short bf8v;   // 8 bf16 (4 VGPRs)
typedef __attribute__((ext_vector_type(16))) float f32x16; // MFMA 32x32 acc

// ws layout (float offsets):
//   nrm  @0       (1024)
//   DT   @1024    (122880)
//   Bph  @123904  (61440)
//   Bpl  @185344  (61440)
//   keys @246784  (262144 ints)
//   partials @508928 (512)

__device__ __forceinline__ void bsplit(float v, short& h, short& lo) {
  unsigned u = __float_as_uint(v);
  unsigned hb = (u + 0x7fffu + ((u >> 16) & 1u)) >> 16;   // RNE to bf16
  float hf = __uint_as_float(hb << 16);
  float lf = v - hf;
  unsigned u2 = __float_as_uint(lf);
  unsigned lb = (u2 + 0x7fffu + ((u2 >> 16) & 1u)) >> 16;
  h = (short)hb; lo = (short)lb;
}

// ---- kernel 0 (fused): blocks 0..59 pack dicts; blocks 60..63 norms + DT ----
__global__ void vq_prep(const float* __restrict__ D0, const float* __restrict__ D1,
                        const float* __restrict__ D2, const float* __restrict__ D3,
                        float* __restrict__ nrm, float* __restrict__ DT,
                        bf8v* __restrict__ Bph, bf8v* __restrict__ Bpl) {
  const int b = blockIdx.x;
  if (b < 60) {
    int g = b * 256 + threadIdx.x;                  // 15360 exact
    int T = g >> 9, c = (g >> 6) & 7, l = g & 63;
    int col = T * 32 + (l & 31);
    int k0 = c * 16 + (l >> 5) * 8;
    const float* D; int K, cb;
    if (col < 64)       { D = D0; K = 64;  cb = col; }
    else if (col < 192) { D = D1; K = 128; cb = col - 64; }
    else if (col < 448) { D = D2; K = 256; cb = col - 192; }
    else                { D = D3; K = 512; cb = col - 448; }
    short h0,h1,h2,h3,h4,h5,h6,h7, q0,q1,q2,q3,q4,q5,q6,q7;
    bsplit(D[(k0+0)*K + cb], h0, q0);
    bsplit(D[(k0+1)*K + cb], h1, q1);
    bsplit(D[(k0+2)*K + cb], h2, q2);
    bsplit(D[(k0+3)*K + cb], h3, q3);
    bsplit(D[(k0+4)*K + cb], h4, q4);
    bsplit(D[(k0+5)*K + cb], h5, q5);
    bsplit(D[(k0+6)*K + cb], h6, q6);
    bsplit(D[(k0+7)*K + cb], h7, q7);
    Bph[g] = (bf8v){h0,h1,h2,h3,h4,h5,h6,h7};
    Bpl[g] = (bf8v){q0,q1,q2,q3,q4,q5,q6,q7};
  } else {
    int g = (b - 60) * 256 + threadIdx.x;
    if (g >= 960) return;
    const float* D; int K, k; float* T;
    if (g < 64)       { D = D0; K = 64;  k = g;       T = DT; }
    else if (g < 192) { D = D1; K = 128; k = g - 64;  T = DT + 8192; }
    else if (g < 448) { D = D2; K = 256; k = g - 192; T = DT + 24576; }
    else              { D = D3; K = 512; k = g - 448; T = DT + 57344; }
    float s = 0.f;
    for (int c = 0; c < 128; ++c) { float v = D[c*K+k]; s = fmaf(v,v,s); T[k*128+c] = v; }
    nrm[g] = s;
  }
}

#define MK8(U0, U1, HD, LD) { \
  short h0,h1,h2,h3,h4,h5,h6,h7, q0,q1,q2,q3,q4,q5,q6,q7; \
  bsplit(U0.x,h0,q0); bsplit(U0.y,h1,q1); bsplit(U0.z,h2,q2); bsplit(U0.w,h3,q3); \
  bsplit(U1.x,h4,q4); bsplit(U1.y,h5,q5); bsplit(U1.z,h6,q6); bsplit(U1.w,h7,q7); \
  HD = (bf8v){h0,h1,h2,h3,h4,h5,h6,h7}; \
  LD = (bf8v){q0,q1,q2,q3,q4,q5,q6,q7}; }

#define MFMA32(AC, AF, BF) AC = __builtin_amdgcn_mfma_f32_32x32x16_bf16((AF), (BF), (AC), 0, 0, 0)

// prefetch tile TT's packed B (16 KB) into 4 named regs per thread (coalesced 16B)
#define PF_T(TT) { \
  const bf8v* __restrict__ gh = Bph + (TT) * 512; \
  const bf8v* __restrict__ gl = Bpl + (TT) * 512; \
  pf0 = gh[t]; pf1 = gh[256 + t]; pf2 = gl[t]; pf3 = gl[256 + t]; }

// write prefetched regs into LDS buffer BF (contiguous 16B/thread -> conflict-free b128)
#define STORE_T(BF) { \
  BL[BF][t] = pf0; BL[BF][256 + t] = pf1; BL[BF][512 + t] = pf2; BL[BF][768 + t] = pf3; }

// one 32-col tile from LDS buffer BF: 16 ds_read_b128 + 24 MFMAs + criterion
#define COMPUTE_T(T, BF) { \
  f32x16 ae = zero16, ao = zero16; \
  _Pragma("unroll") \
  for (int cp = 0; cp < 4; ++cp) { \
    const int ce = 2*cp, co = 2*cp+1; \
    bf8v bhe = BL[BF][ce*64 + l]; bf8v bho = BL[BF][co*64 + l]; \
    bf8v ble = BL[BF][512 + ce*64 + l]; bf8v blo = BL[BF][512 + co*64 + l]; \
    MFMA32(ae, Ah[ce], bhe); MFMA32(ao, Ah[co], bho); \
    MFMA32(ae, Al[ce], bhe); MFMA32(ao, Al[co], bho); \
    MFMA32(ae, Ah[ce], ble); MFMA32(ao, Ah[co], blo); \
  } \
  f32x16 sv = ae + ao; \
  const float nv = nrm_g[(T)*32 + (l & 31)]; \
  const int colT = (T)*32 + (l & 31); \
  _Pragma("unroll") \
  for (int r = 0; r < 16; ++r) { \
    float c0 = fmaf(-2.f, sv[r], nv); \
    if (c0 < bc[r]) { bc[r] = c0; bk[r] = colT; } } }

// dbuf pipeline round, ONE barrier per tile (r15 structure, bench-best)
#define ROUND_T(T) { \
  if ((T) < 29) { \
    STORE_T(((T) + 1) & 1); \
    const int TN = ((T) + 2 <= 29) ? (T) + 2 : 29; \
    PF_T(TN); \
  } \
  COMPUTE_T(T, (T) & 1) \
  __syncthreads(); }

// lex-min argmin flush; keys -> global; closed-form loss; reset
#define FLUSHG(DICTID, BASE, GAM) { \
  _Pragma("unroll") \
  for (int r = 0; r < 16; ++r) { \
    float b0 = bc[r]; int K0 = bk[r]; \
    _Pragma("unroll") \
    for (int m = 1; m <= 16; m <<= 1) { \
      float pb = __shfl_xor(b0, m); int pk = __shfl_xor(K0, m); \
      if (pb < b0 || (pb == b0 && pk < K0)) { b0 = pb; K0 = pk; } } \
    if ((l & 31) == 0) { \
      const int ro = (r & 3) + 8 * (r >> 2) + 4 * hl; \
      keys[((rowbase + ro) << 2) | (DICTID)] = K0 - (BASE); \
      const float nst = nrm_g[K0]; \
      /* gamma*a*((a-1)*n + crit) == gamma*(a^2 n - 2 a s) */ \
      lossacc = fmaf((GAM) * a, fmaf(am1, nst, b0), lossacc); } \
    bc[r] = 1e30f; bk[r] = 0; } }

// ---- kernel 1: MFMA scoring + argmin + loss. 512 blocks x 256 thr (r15 schedule) ----
__global__ __launch_bounds__(256, 2) void vq_mfma(
    const float* __restrict__ x,
    const bf8v* __restrict__ Bph, const bf8v* __restrict__ Bpl,
    const float* __restrict__ nrm_g,
    const float* __restrict__ alpha_p, const float* __restrict__ gamma_p,
    int* __restrict__ keys, float* __restrict__ partials)
{
  __shared__ bf8v  BL[2][1024];   // 32 KB double-buffered B tile
  __shared__ float lossW[4];

  const int t = threadIdx.x;
  const int w = t >> 6, l = t & 63;
  const int hl = l >> 5;
  const int rowbase = blockIdx.x * 128 + w * 32;

  const float a   = alpha_p[0];
  const float am1 = a - 1.f;
  const float g0 = gamma_p[0], g1 = gamma_p[1], g2 = gamma_p[2], g3 = gamma_p[3];
  const float gsum = g0 + g1 + g2 + g3;

  // A fragments straight from global; exact xsq accumulated pre-split
  bf8v Ah[8], Al[8];
  float xsqh = 0.f;
  {
    const float* __restrict__ xr = x + (size_t)(rowbase + (l & 31)) * CDIM + hl * 8;
    #pragma unroll
    for (int c = 0; c < 8; ++c) {
      float4 u0 = *(const float4*)(xr + c * 16);
      float4 u1 = *(const float4*)(xr + c * 16 + 4);
      xsqh = fmaf(u0.x,u0.x, xsqh); xsqh = fmaf(u0.y,u0.y, xsqh);
      xsqh = fmaf(u0.z,u0.z, xsqh); xsqh = fmaf(u0.w,u0.w, xsqh);
      xsqh = fmaf(u1.x,u1.x, xsqh); xsqh = fmaf(u1.y,u1.y, xsqh);
      xsqh = fmaf(u1.z,u1.z, xsqh); xsqh = fmaf(u1.w,u1.w, xsqh);
      MK8(u0, u1, Ah[c], Al[c])
    }
  }
  float xs_ = xsqh;
  #pragma unroll
  for (int m = 1; m <= 32; m <<= 1) xs_ += __shfl_xor(xs_, m);

  f32x16 zero16;
  #pragma unroll
  for (int i = 0; i < 16; ++i) zero16[i] = 0.f;

  float bc[16]; int bk[16];
  #pragma unroll
  for (int r = 0; r < 16; ++r) { bc[r] = 1e30f; bk[r] = 0; }
  float lossacc = 0.f;

  bf8v pf0, pf1, pf2, pf3;
  PF_T(0)
  STORE_T(0)
  PF_T(1)
  __syncthreads();

  // dict boundaries at tiles {2,6,14,30}
  ROUND_T(0) ROUND_T(1)
  FLUSHG(0, 0, g0)
  for (int T = 2; T < 6; ++T) ROUND_T(T)
  FLUSHG(1, 64, g1)
  for (int T = 6; T < 14; ++T) ROUND_T(T)
  FLUSHG(2, 192, g2)
  for (int T = 14; T < 30; ++T) ROUND_T(T)
  FLUSHG(3, 448, g3)

  // loss: flush terms live in lanes 0 and 32; add gsum * wave xsq once
  {
    float wl = lossacc + __shfl_xor(lossacc, 32);
    if (l == 0) lossW[w] = fmaf(gsum, xs_, wl);
  }
  __syncthreads();
  if (t == 0) partials[blockIdx.x] = lossW[0] + lossW[1] + lossW[2] + lossW[3];
}

// ---- kernel 2: out-only gather (no x read, no loss). 2048 blocks x 256 thr ----
__global__ __launch_bounds__(256, 8) void vq_merge(
    const float* __restrict__ DT, const int* __restrict__ keys,
    const float* __restrict__ alpha_p, const float* __restrict__ gamma_p,
    float* __restrict__ out)
{
  __shared__ int kk[32][4];
  const int t = threadIdx.x;
  const int row0 = blockIdx.x * 32;
  if (t < 128) kk[t >> 2][t & 3] = keys[((row0 + (t >> 2)) << 2) | (t & 3)];
  __syncthreads();
  const float a = alpha_p[0];
  const float g0 = gamma_p[0], g1 = gamma_p[1], g2 = gamma_p[2], g3 = gamma_p[3];
  #pragma unroll
  for (int j = 0; j < 4; ++j) {
    const int f = j * 256 + t;
    const int r = f >> 5, c4 = (f & 31) * 4;
    const size_t off = (size_t)(row0 + r) * CDIM + c4;
    const float4 d0 = *(const float4*)(DT +         kk[r][0] * 128 + c4);
    const float4 d1 = *(const float4*)(DT +  8192 + kk[r][1] * 128 + c4);
    const float4 d2 = *(const float4*)(DT + 24576 + kk[r][2] * 128 + c4);
    const float4 d3 = *(const float4*)(DT + 57344 + kk[r][3] * 128 + c4);
    float4 o;
    o.x = a * (g0*d0.x + g1*d1.x + g2*d2.x + g3*d3.x);
    o.y = a * (g0*d0.y + g1*d1.y + g2*d2.y + g3*d3.y);
    o.z = a * (g0*d0.z + g1*d1.z + g2*d2.z + g3*d3.z);
    o.w = a * (g0*d0.w + g1*d1.w + g2*d2.w + g3*d3.w);
    *(float4*)(out + off) = o;
  }
}

// ---- kernel 3: final deterministic loss reduction (512 partials) ----
__global__ void vq_loss(const float* __restrict__ partials, float* __restrict__ lossp) {
  __shared__ float wr[4];
  const int t = threadIdx.x;
  float v = partials[t] + partials[t + 256];
  #pragma unroll
  for (int off = 32; off > 0; off >>= 1) v += __shfl_down(v, off);
  if ((t & 63) == 0) wr[t >> 6] = v;
  __syncthreads();
  if (t == 0) lossp[0] = (wr[0] + wr[1] + wr[2] + wr[3]) * (1.25f / 8388608.f);
}

extern "C" void kernel_launch(void* const* d_in, const int* in_sizes, int n_in,
                              void* d_out, int out_size, void* d_ws, size_t ws_size,
                              hipStream_t stream) {
  const float* x  = (const float*)d_in[0];
  const float* D0 = (const float*)d_in[1];
  const float* D1 = (const float*)d_in[2];
  const float* D2 = (const float*)d_in[3];
  const float* D3 = (const float*)d_in[4];
  const float* alpha = (const float*)d_in[5];
  const float* gamma = (const float*)d_in[6];
  float* out = (float*)d_out;

  float* ws  = (float*)d_ws;
  float* nrm = ws;                         // 1024
  float* DT  = ws + 1024;                  // 122880
  bf8v*  Bph = (bf8v*)(ws + 123904);       // 61440 floats
  bf8v*  Bpl = (bf8v*)(ws + 185344);       // 61440 floats
  int*  keys = (int*)(ws + 246784);        // 262144 ints
  float* partials = ws + 508928;           // 512

  vq_prep<<<64, 256, 0, stream>>>(D0, D1, D2, D3, nrm, DT, Bph, Bpl);
  vq_mfma<<<512, 256, 0, stream>>>(x, Bph, Bpl, nrm, alpha, gamma, keys, partials);
  vq_merge<<<2048, 256, 0, stream>>>(DT, keys, alpha, gamma, out);
  vq_loss<<<1, 256, 0, stream>>>(partials, out + NC);
}